// Round 5
// baseline (378.729 us; speedup 1.0000x reference)
//
#include <hip/hip_runtime.h>
#include <math.h>

#define NUMB 64
#define PP 8732
#define CC 81
#define KK 16
#define CTILE 64
#define NTILES 137                 // ceil(PP/CTILE)
#define NVALS 35                   // ceil(PP/256)
#define MT 1024                    // match threads

// ---------------------------------------------------------------- match
// One block per image, 1024 threads. Truths in dedicated __shared__ arrays
// (separate objects -> no aliasing with btov/btidx stores -> hoistable;
// per-lane ds_read is exec-mask safe, unlike ds_bpermute/__shfl).
__global__ __launch_bounds__(MT) void match_kernel(
    const float* __restrict__ loc_data,
    const float* __restrict__ priors,
    const float* __restrict__ targets,
    unsigned char* __restrict__ conf_t,
    float* __restrict__ lossl_row,
    int* __restrict__ numpos_row,
    float* __restrict__ accs)
{
  const int b = blockIdx.x, tid = threadIdx.x;
  const int lane = tid & 63, wid = tid >> 6;      // 16 waves
  __shared__ float tx1[KK], ty1[KK], tx2[KK], ty2[KK], tlab[KK], tarea[KK];
  __shared__ float btov[PP];
  __shared__ unsigned char btidx[PP];
  __shared__ float wv[16 * KK];
  __shared__ int   wi[16 * KK];
  __shared__ float fv[KK];
  __shared__ int   fi[KK];
  __shared__ float redf[16];
  __shared__ int   redi[16];

  if (b == 0 && tid < 4) accs[tid] = 0.f;   // zero global accumulators

  if (tid < KK) {
    const float* t = targets + (size_t)(b * KK + tid) * 6;
    float x1 = t[2], y1 = t[3], x2 = t[4], y2 = t[5];
    tx1[tid] = x1; ty1[tid] = y1; tx2[tid] = x2; ty2[tid] = y2;
    tlab[tid] = t[1];
    tarea[tid] = (x2 - x1) * (y2 - y1);
  }
  __syncthreads();

  float bpv[KK]; int bpi[KK];
#pragma unroll
  for (int k = 0; k < KK; k++) { bpv[k] = -1.f; bpi[k] = 0x7fffffff; }

  const float4* pri4 = (const float4*)priors;
  for (int p = tid; p < PP; p += MT) {
    float4 pr = pri4[p];
    float areab = (pr.z - pr.x) * (pr.w - pr.y);
    float bestv = -1.f; int besti = 0;
#pragma unroll
    for (int k = 0; k < KK; k++) {
      float iw = fminf(tx2[k], pr.z) - fmaxf(tx1[k], pr.x); iw = fmaxf(iw, 0.f);
      float ih = fminf(ty2[k], pr.w) - fmaxf(ty1[k], pr.y); ih = fmaxf(ih, 0.f);
      float inter = iw * ih;
      float iou = inter / (tarea[k] + areab - inter);
      if (iou > bestv) { bestv = iou; besti = k; }     // first max over k
      if (iou > bpv[k]) { bpv[k] = iou; bpi[k] = p; }  // first max over p
    }
    btov[p] = bestv;
    btidx[p] = (unsigned char)besti;
  }

#pragma unroll
  for (int k = 0; k < KK; k++) {
    float v = bpv[k]; int i = bpi[k];
    for (int off = 32; off > 0; off >>= 1) {
      float v2 = __shfl_down(v, off);
      int   i2 = __shfl_down(i, off);
      if (v2 > v || (v2 == v && i2 < i)) { v = v2; i = i2; }
    }
    if (lane == 0) { wv[wid * KK + k] = v; wi[wid * KK + k] = i; }
  }
  __syncthreads();

  if (tid < KK) {   // per-truth reduce over 16 waves (first-occurrence ties)
    float v = wv[tid]; int i = wi[tid];
    for (int w = 1; w < 16; w++) {
      float v2 = wv[w * KK + tid]; int i2 = wi[w * KK + tid];
      if (v2 > v || (v2 == v && i2 < i)) { v = v2; i = i2; }
    }
    fv[tid] = v; fi[tid] = i;
  }
  __syncthreads();
  if (tid == 0) {   // serial scatter, k ascending => last write wins
    for (int k = 0; k < KK; k++) {
      btidx[fi[k]] = (unsigned char)k;
      btov[fi[k]] = fv[k];
    }
  }
  __syncthreads();

  float lossl = 0.f; int npos = 0;
  const float4* loc4 = (const float4*)loc_data;
  for (int p = tid; p < PP; p += MT) {
    int bt = btidx[p];
    float ov = btov[p];
    int cls = (ov < 0.5f) ? 0 : (int)tlab[bt];      // per-lane LDS read: exec-safe
    conf_t[(size_t)b * PP + p] = (unsigned char)cls;
    if (cls > 0) {
      npos++;
      float4 pr = pri4[p];
      float pcx = (pr.x + pr.z) * 0.5f, pcy = (pr.y + pr.w) * 0.5f;
      float pw = pr.z - pr.x, ph = pr.w - pr.y;
      float mx1 = tx1[bt], my1 = ty1[bt], mx2 = tx2[bt], my2 = ty2[bt];
      float g[4];
      g[0] = ((mx1 + mx2) * 0.5f - pcx) / (0.1f * pw);
      g[1] = ((my1 + my2) * 0.5f - pcy) / (0.1f * ph);
      g[2] = logf((mx2 - mx1) / pw) / 0.2f;
      g[3] = logf((my2 - my1) / ph) / 0.2f;
      float4 l4 = loc4[(size_t)b * PP + p];
      float lv[4] = { l4.x, l4.y, l4.z, l4.w };
#pragma unroll
      for (int j = 0; j < 4; j++) {
        float d = lv[j] - g[j];
        float ad = fabsf(d);
        lossl += (ad < 1.f) ? 0.5f * d * d : ad - 0.5f;
      }
    }
  }
  float lv2 = lossl;
  for (int off = 32; off > 0; off >>= 1) lv2 += __shfl_down(lv2, off);
  int nv = npos;
  for (int off = 32; off > 0; off >>= 1) nv += __shfl_down(nv, off);
  if (lane == 0) { redf[wid] = lv2; redi[wid] = nv; }
  __syncthreads();
  if (tid == 0) {
    float sf = 0.f; int si = 0;
    for (int w = 0; w < 16; w++) { sf += redf[w]; si += redi[w]; }
    lossl_row[b] = sf;
    numpos_row[b] = si;
  }
}

// ---------------------------------------------------------------- lse
// 137x64 blocks, 256 threads. Async staging; loop structured so every
// issued global_load_lds has exec!=0 and an in-bounds wave-uniform LDS base.
__global__ __launch_bounds__(256) void lse_kernel(
    const float* __restrict__ conf_data,
    float* __restrict__ lse_ws)
{
  __shared__ float sh[CTILE * CC + 64];   // pad: stray 16B writes stay in-bounds
  const int tile = blockIdx.x, b = blockIdx.y, tid = threadIdx.x;
  const int lane = tid & 63, wid = tid >> 6;
  const int p0 = tile * CTILE;
  const int count = min(CTILE, PP - p0);
  const int n4 = count * CC / 4;     // 1296 or 567
  const float4* g4 = (const float4*)(conf_data + ((size_t)b * PP + p0) * CC);
  float4* s4 = (float4*)sh;
  for (int base = wid << 6; base < n4; base += 256) {   // wave-uniform base < n4
    if (base + lane < n4) {
      __builtin_amdgcn_global_load_lds(
          (__attribute__((address_space(1))) const void*)(g4 + base + lane),
          (__attribute__((address_space(3))) void*)(s4 + base),
          16, 0, 0);
    }
  }
  __syncthreads();
  const int r = tid >> 2, h = tid & 3;      // 4 threads per row
  if (r < count) {
    const float* row = sh + r * CC;
    const int c0 = h * 21;
    const int c1 = (h == 3) ? CC : (c0 + 21);
    float s = 0.f;
    for (int c = c0; c < c1; c++) s += __expf(row[c]);
    s += __shfl_xor(s, 1);
    s += __shfl_xor(s, 2);
    if (h == 0) lse_ws[(size_t)b * PP + p0 + r] = __logf(s);
  }
}

// ---------------------------------------------------------------- mine+final
__global__ __launch_bounds__(256) void mine_final(
    const float* __restrict__ conf_data,
    const float* __restrict__ lse_ws,
    const unsigned char* __restrict__ conf_t,
    const float* __restrict__ lossl_row,
    const int* __restrict__ numpos_row,
    float* __restrict__ accs,
    float* __restrict__ out)
{
  const int b = blockIdx.x, tid = threadIdx.x;
  const int lane = tid & 63, wid = tid >> 6;
  __shared__ float shf[4];
  __shared__ int shi[4];

  float vals[NVALS];
  float posce = 0.f;
  const size_t rowbase = (size_t)b * PP;
#pragma unroll
  for (int i = 0; i < NVALS; i++) {
    const int p = i * 256 + tid;
    float v = 0.f;
    if (i < NVALS - 1 || p < PP) {
      float lse = lse_ws[rowbase + p];
      int cls = conf_t[rowbase + p];
      float ce = lse - conf_data[(rowbase + p) * CC + cls];
      if (cls > 0) posce += ce; else v = ce;
    }
    vals[i] = v;
  }

  for (int off = 32; off > 0; off >>= 1) posce += __shfl_down(posce, off);
  if (lane == 0) shf[wid] = posce;
  __syncthreads();
  float lossc = shf[0] + shf[1] + shf[2] + shf[3];

  const int npos = numpos_row[b];
  const int k = min(3 * npos, PP - 1);

  if (k > 0) {
    unsigned lo = 0u, hi = 0x7F7FFFFFu;
    while (lo < hi) {
      unsigned mid = lo + ((hi - lo) >> 1);
      float t = __uint_as_float(mid);
      int cnt = 0;
#pragma unroll
      for (int i = 0; i < NVALS; i++) cnt += (vals[i] > t) ? 1 : 0;
      for (int off = 32; off > 0; off >>= 1) cnt += __shfl_down(cnt, off);
      if (lane == 0) shi[wid] = cnt;
      __syncthreads();
      cnt = shi[0] + shi[1] + shi[2] + shi[3];
      __syncthreads();
      if (cnt < k) hi = mid; else lo = mid + 1;
    }
    float v = __uint_as_float(lo);
    float sgt = 0.f; int cgt = 0;
#pragma unroll
    for (int i = 0; i < NVALS; i++) {
      float x = vals[i];
      if (x > v) { sgt += x; cgt++; }
    }
    for (int off = 32; off > 0; off >>= 1) {
      sgt += __shfl_down(sgt, off);
      cgt += __shfl_down(cgt, off);
    }
    if (lane == 0) { shf[wid] = sgt; shi[wid] = cgt; }
    __syncthreads();
    float sgt_t = shf[0] + shf[1] + shf[2] + shf[3];
    int cgt_t = shi[0] + shi[1] + shi[2] + shi[3];
    lossc += sgt_t + (float)(k - cgt_t) * v;   // ties at v contribute v each
  }

  if (tid == 0) {
    atomicAdd(&accs[0], lossl_row[b]);
    atomicAdd(&accs[1], lossc);
    atomicAdd(&accs[2], (float)npos);
    __threadfence();
    unsigned old = atomicAdd((unsigned int*)&accs[3], 1u);
    if (old == NUMB - 1) {
      float L = atomicAdd(&accs[0], 0.f);
      float C = atomicAdd(&accs[1], 0.f);
      float N = atomicAdd(&accs[2], 0.f);
      float n = fmaxf(N, 1.f);
      out[0] = L / n;   // LOC_W = 1.0
      out[1] = C / n;
    }
  }
}

extern "C" void kernel_launch(void* const* d_in, const int* in_sizes, int n_in,
                              void* d_out, int out_size, void* d_ws, size_t ws_size,
                              hipStream_t stream) {
  const float* loc     = (const float*)d_in[0];
  const float* conf    = (const float*)d_in[1];
  const float* priors  = (const float*)d_in[2];
  const float* targets = (const float*)d_in[3];
  float* out = (float*)d_out;

  char* ws = (char*)d_ws;
  float* lse_ws = (float*)ws;                                  // 558848 f32
  unsigned char* conft = (unsigned char*)(ws + (size_t)558848 * 4);
  float* lossl_row = (float*)(ws + (size_t)558848 * 5);
  int* numpos_row = (int*)(lossl_row + 64);
  float* accs = (float*)(numpos_row + 64);                     // [L, C, N, counter]

  match_kernel<<<NUMB, MT, 0, stream>>>(loc, priors, targets, conft,
                                        lossl_row, numpos_row, accs);
  lse_kernel<<<dim3(NTILES, NUMB), 256, 0, stream>>>(conf, lse_ws);
  mine_final<<<NUMB, 256, 0, stream>>>(
      conf, lse_ws, conft, lossl_row, numpos_row, accs, out);
}

// Round 6
// 322.259 us; speedup vs baseline: 1.1752x; 1.1752x over previous
//
#include <hip/hip_runtime.h>
#include <math.h>

#define NUMB 64
#define PP 8732
#define CC 81
#define KK 16
#define CTILE 64
#define NTILES 137                 // ceil(PP/CTILE)
#define NVALS 35                   // ceil(PP/256)

// smooth-L1 of encoded offset vs loc prediction for one prior/truth pair.
// Must be used for BOTH the phase-1 add and the correction subtract so the
// two are bitwise identical and cancel exactly.
__device__ __forceinline__ float sl1enc(float4 pr, float4 l4,
    float mx1, float my1, float mx2, float my2) {
  float pcx = (pr.x + pr.z) * 0.5f, pcy = (pr.y + pr.w) * 0.5f;
  float pw = pr.z - pr.x, ph = pr.w - pr.y;
  float g[4];
  g[0] = ((mx1 + mx2) * 0.5f - pcx) / (0.1f * pw);
  g[1] = ((my1 + my2) * 0.5f - pcy) / (0.1f * ph);
  g[2] = logf((mx2 - mx1) / pw) / 0.2f;
  g[3] = logf((my2 - my1) / ph) / 0.2f;
  float lv[4] = { l4.x, l4.y, l4.z, l4.w };
  float s = 0.f;
#pragma unroll
  for (int j = 0; j < 4; j++) {
    float d = lv[j] - g[j];
    float ad = fabsf(d);
    s += (ad < 1.f) ? 0.5f * d * d : ad - 0.5f;
  }
  return s;
}

// ---------------------------------------------------------------- kernel 1
// blocks [0,64): match for image b — stateless streaming + 16-lane correction
// blocks [64, 8832): lse tiles (no dependency on match -> full overlap)
__global__ __launch_bounds__(256) void fused_main(
    const float* __restrict__ conf_data,
    const float* __restrict__ loc_data,
    const float* __restrict__ priors,
    const float* __restrict__ targets,
    float* __restrict__ lse_ws,
    unsigned char* __restrict__ conf_t,
    float* __restrict__ lossl_row,
    int* __restrict__ numpos_row,
    float* __restrict__ accs)
{
  __shared__ float sh[CTILE * CC + 16];     // lse tile (~21 KB) — dominant LDS
  __shared__ float s_lab[KK], s_x1[KK], s_y1[KK], s_x2[KK], s_y2[KK];
  __shared__ float wv[4 * KK]; __shared__ int wi[4 * KK];
  __shared__ float fv[KK];     __shared__ int fi[KK];
  __shared__ float redf[4];    __shared__ int redi[4];

  const int tid = threadIdx.x;
  const int lane = tid & 63, wid = tid >> 6;

  if (blockIdx.x >= NUMB) {
    // ---------------- lse tile (identical to round-5 lse_kernel) ----------
    const int t = blockIdx.x - NUMB;
    const int tile = t % NTILES, b = t / NTILES;
    const int p0 = tile * CTILE;
    const int count = min(CTILE, PP - p0);
    const int n4 = count * CC / 4;          // 1296 or 567
    const float4* g4 = (const float4*)(conf_data + ((size_t)b * PP + p0) * CC);
    float4* s4 = (float4*)sh;
    for (int base = wid << 6; base < n4; base += 256) {   // wave-uniform base
      if (base + lane < n4) {
        __builtin_amdgcn_global_load_lds(
            (__attribute__((address_space(1))) const void*)(g4 + base + lane),
            (__attribute__((address_space(3))) void*)(s4 + base),
            16, 0, 0);
      }
    }
    __syncthreads();
    const int r = tid >> 2, h = tid & 3;    // 4 threads per row
    if (r < count) {
      const float* row = sh + r * CC;
      const int c0 = h * 21;
      const int c1 = (h == 3) ? CC : (c0 + 21);
      float s = 0.f;
      for (int c = c0; c < c1; c++) s += __expf(row[c]);
      s += __shfl_xor(s, 1);
      s += __shfl_xor(s, 2);
      if (h == 0) lse_ws[(size_t)b * PP + p0 + r] = __logf(s);
    }
    return;
  }

  // ---------------- match (b = blockIdx.x) ----------------
  const int b = blockIdx.x;
  const size_t rowbase = (size_t)b * PP;

  if (b == 0 && tid < 4) accs[tid] = 0.f;   // zero global accumulators

  if (tid < KK) {                           // per-lane-index access copy (LDS)
    const float* t = targets + (size_t)(b * KK + tid) * 6;
    s_lab[tid] = t[1];
    s_x1[tid] = t[2]; s_y1[tid] = t[3]; s_x2[tid] = t[4]; s_y2[tid] = t[5];
  }
  __syncthreads();

  // block-uniform truth copies -> scalar regs (hoisted out of the p-loop)
  float ax1[KK], ay1[KK], ax2[KK], ay2[KK], aar[KK];
#pragma unroll
  for (int k = 0; k < KK; k++) {
    const float* t = targets + (size_t)(b * KK + k) * 6;
    ax1[k] = t[2]; ay1[k] = t[3]; ax2[k] = t[4]; ay2[k] = t[5];
    aar[k] = (ax2[k] - ax1[k]) * (ay2[k] - ay1[k]);
  }

  float bpv[KK]; int bpi[KK];
#pragma unroll
  for (int k = 0; k < KK; k++) { bpv[k] = -1.f; bpi[k] = 0x7fffffff; }

  const float4* pri4 = (const float4*)priors;
  const float4* loc4 = (const float4*)loc_data;
  float lossl = 0.f; int npos = 0;

  for (int i = 0; i < NVALS; i++) {
    const int p = i * 256 + tid;
    if (p < PP) {
      float4 pr = pri4[p];
      float areab = (pr.z - pr.x) * (pr.w - pr.y);
      float bestv = -1.f; int besti = 0;
#pragma unroll
      for (int k = 0; k < KK; k++) {
        float iw = fminf(ax2[k], pr.z) - fmaxf(ax1[k], pr.x); iw = fmaxf(iw, 0.f);
        float ih = fminf(ay2[k], pr.w) - fmaxf(ay1[k], pr.y); ih = fmaxf(ih, 0.f);
        float inter = iw * ih;
        float iou = inter / (aar[k] + areab - inter);
        if (iou > bestv) { bestv = iou; besti = k; }     // first max over k
        if (iou > bpv[k]) { bpv[k] = iou; bpi[k] = p; }  // first max over p
      }
      int cls = (bestv < 0.5f) ? 0 : (int)s_lab[besti];
      conf_t[rowbase + p] = (unsigned char)cls;
      if (cls > 0) {
        npos++;
        lossl += sl1enc(pr, loc4[rowbase + p],
                        s_x1[besti], s_y1[besti], s_x2[besti], s_y2[besti]);
      }
    }
  }

  // per-truth best prior: wave reduce -> 4 waves -> final (first-occurrence ties)
#pragma unroll
  for (int k = 0; k < KK; k++) {
    float v = bpv[k]; int i = bpi[k];
    for (int off = 32; off > 0; off >>= 1) {
      float v2 = __shfl_down(v, off);
      int   i2 = __shfl_down(i, off);
      if (v2 > v || (v2 == v && i2 < i)) { v = v2; i = i2; }
    }
    if (lane == 0) { wv[wid * KK + k] = v; wi[wid * KK + k] = i; }
  }
  __syncthreads();
  if (tid < KK) {
    float v = wv[tid]; int i = wi[tid];
    for (int w = 1; w < 4; w++) {
      float v2 = wv[w * KK + tid]; int i2 = wi[w * KK + tid];
      if (v2 > v || (v2 == v && i2 < i)) { v = v2; i = i2; }
    }
    fv[tid] = v; fi[tid] = i;
  }
  __syncthreads();

  // correction: force-assign touches <=16 priors; lane k fixes truth k's prior.
  // Dedupe keeps the highest k per prior (last-write-wins like the reference).
  if (wid == 0) {
    float dl = 0.f; int dn = 0;
    if (lane < KK) {
      const int pstar = fi[lane];
      bool act = true;
      for (int k2 = lane + 1; k2 < KK; k2++) if (fi[k2] == pstar) act = false;
      if (act) {
        float4 pr = pri4[pstar];
        float areab = (pr.z - pr.x) * (pr.w - pr.y);
        float ovo = -1.f; int bto = 0;                 // pre-force best truth
#pragma unroll
        for (int k = 0; k < KK; k++) {
          float iw = fminf(ax2[k], pr.z) - fmaxf(ax1[k], pr.x); iw = fmaxf(iw, 0.f);
          float ih = fminf(ay2[k], pr.w) - fmaxf(ay1[k], pr.y); ih = fmaxf(ih, 0.f);
          float inter = iw * ih;
          float iou = inter / (aar[k] + areab - inter);
          if (iou > ovo) { ovo = iou; bto = k; }
        }
        int clso = (ovo < 0.5f) ? 0 : (int)s_lab[bto];
        float ovn = fv[lane];
        int clsn = (ovn < 0.5f) ? 0 : (int)s_lab[lane];
        conf_t[rowbase + pstar] = (unsigned char)clsn;
        float4 l4 = loc4[rowbase + pstar];
        if (clso > 0) { dn--; dl -= sl1enc(pr, l4, s_x1[bto], s_y1[bto], s_x2[bto], s_y2[bto]); }
        if (clsn > 0) { dn++; dl += sl1enc(pr, l4, s_x1[lane], s_y1[lane], s_x2[lane], s_y2[lane]); }
      }
    }
    lossl += dl; npos += dn;
  }

  // block reduce lossl / npos
  float lv2 = lossl;
  for (int off = 32; off > 0; off >>= 1) lv2 += __shfl_down(lv2, off);
  int nv = npos;
  for (int off = 32; off > 0; off >>= 1) nv += __shfl_down(nv, off);
  if (lane == 0) { redf[wid] = lv2; redi[wid] = nv; }
  __syncthreads();
  if (tid == 0) {
    lossl_row[b] = redf[0] + redf[1] + redf[2] + redf[3];
    numpos_row[b] = redi[0] + redi[1] + redi[2] + redi[3];
  }
}

// ---------------------------------------------------------------- kernel 2
// gather class logit (L2/L3-hot) -> ce, register-resident exact top-k select,
// grid reduction via atomics + completion counter -> out. (Round-5 verified.)
__global__ __launch_bounds__(256) void mine_final(
    const float* __restrict__ conf_data,
    const float* __restrict__ lse_ws,
    const unsigned char* __restrict__ conf_t,
    const float* __restrict__ lossl_row,
    const int* __restrict__ numpos_row,
    float* __restrict__ accs,
    float* __restrict__ out)
{
  const int b = blockIdx.x, tid = threadIdx.x;
  const int lane = tid & 63, wid = tid >> 6;
  __shared__ float shf[4];
  __shared__ int shi[4];

  float vals[NVALS];
  float posce = 0.f;
  const size_t rowbase = (size_t)b * PP;
#pragma unroll
  for (int i = 0; i < NVALS; i++) {
    const int p = i * 256 + tid;
    float v = 0.f;
    if (i < NVALS - 1 || p < PP) {
      float lse = lse_ws[rowbase + p];
      int cls = conf_t[rowbase + p];
      float ce = lse - conf_data[(rowbase + p) * CC + cls];
      if (cls > 0) posce += ce; else v = ce;
    }
    vals[i] = v;
  }

  for (int off = 32; off > 0; off >>= 1) posce += __shfl_down(posce, off);
  if (lane == 0) shf[wid] = posce;
  __syncthreads();
  float lossc = shf[0] + shf[1] + shf[2] + shf[3];

  const int npos = numpos_row[b];
  const int k = min(3 * npos, PP - 1);

  if (k > 0) {
    unsigned lo = 0u, hi = 0x7F7FFFFFu;
    while (lo < hi) {
      unsigned mid = lo + ((hi - lo) >> 1);
      float t = __uint_as_float(mid);
      int cnt = 0;
#pragma unroll
      for (int i = 0; i < NVALS; i++) cnt += (vals[i] > t) ? 1 : 0;
      for (int off = 32; off > 0; off >>= 1) cnt += __shfl_down(cnt, off);
      if (lane == 0) shi[wid] = cnt;
      __syncthreads();
      cnt = shi[0] + shi[1] + shi[2] + shi[3];
      __syncthreads();
      if (cnt < k) hi = mid; else lo = mid + 1;
    }
    float v = __uint_as_float(lo);
    float sgt = 0.f; int cgt = 0;
#pragma unroll
    for (int i = 0; i < NVALS; i++) {
      float x = vals[i];
      if (x > v) { sgt += x; cgt++; }
    }
    for (int off = 32; off > 0; off >>= 1) {
      sgt += __shfl_down(sgt, off);
      cgt += __shfl_down(cgt, off);
    }
    if (lane == 0) { shf[wid] = sgt; shi[wid] = cgt; }
    __syncthreads();
    float sgt_t = shf[0] + shf[1] + shf[2] + shf[3];
    int cgt_t = shi[0] + shi[1] + shi[2] + shi[3];
    lossc += sgt_t + (float)(k - cgt_t) * v;   // ties at v contribute v each
  }

  if (tid == 0) {
    atomicAdd(&accs[0], lossl_row[b]);
    atomicAdd(&accs[1], lossc);
    atomicAdd(&accs[2], (float)npos);
    __threadfence();
    unsigned old = atomicAdd((unsigned int*)&accs[3], 1u);
    if (old == NUMB - 1) {
      float L = atomicAdd(&accs[0], 0.f);
      float C = atomicAdd(&accs[1], 0.f);
      float N = atomicAdd(&accs[2], 0.f);
      float n = fmaxf(N, 1.f);
      out[0] = L / n;   // LOC_W = 1.0
      out[1] = C / n;
    }
  }
}

extern "C" void kernel_launch(void* const* d_in, const int* in_sizes, int n_in,
                              void* d_out, int out_size, void* d_ws, size_t ws_size,
                              hipStream_t stream) {
  const float* loc     = (const float*)d_in[0];
  const float* conf    = (const float*)d_in[1];
  const float* priors  = (const float*)d_in[2];
  const float* targets = (const float*)d_in[3];
  float* out = (float*)d_out;

  char* ws = (char*)d_ws;
  float* lse_ws = (float*)ws;                                  // 558848 f32
  unsigned char* conft = (unsigned char*)(ws + (size_t)558848 * 4);
  float* lossl_row = (float*)(ws + (size_t)558848 * 5);
  int* numpos_row = (int*)(lossl_row + 64);
  float* accs = (float*)(numpos_row + 64);                     // [L, C, N, counter]

  fused_main<<<NUMB + NTILES * NUMB, 256, 0, stream>>>(
      conf, loc, priors, targets, lse_ws, conft, lossl_row, numpos_row, accs);
  mine_final<<<NUMB, 256, 0, stream>>>(
      conf, lse_ws, conft, lossl_row, numpos_row, accs, out);
}